// Round 7
// baseline (10.545 us; speedup 1.0000x reference)
//
#include <hip/hip_runtime.h>
#include <hip/hip_bf16.h>

// out[i, d] = W[d, idx[i]] + b[d]   (one-hot(idx) @ W^T + b)
// Single-dispatch owner-computes, v3: 512 blocks; block b owns
// (column-group cg = b>>1, idx-half h = b&1).
//   A) stage W[:, c0:c0+32] + bias into LDS transposed (1 float4/thread)
//   B) scan its half of idx (int4, L2-resident) -> LDS match-list
//      (list[CHUNK] can NEVER overflow: provably correct for any input)
//   C) waves drain list: out[i][:] = tile[idx[i]-c0][:] (float2/lane, 512B/wave)
// 1024 thr/block, 2 blocks/CU -> 32 waves/CU; exactly 2 barriers total.

typedef float f32x4 __attribute__((ext_vector_type(4)));
typedef int   i32x4 __attribute__((ext_vector_type(4)));

#define CBLK  32      // env columns per block
#define TSTR  129     // tile stride: 129 % 32 == 1 -> <=2-way banks everywhere
#define CHUNK 8192    // idx ints per block (= B/2); list sized to match

__global__ void __launch_bounds__(1024) onehot_fused_v3(
    const int* __restrict__ idx,
    const float* __restrict__ W,     // [128][ENV]
    const float* __restrict__ bias,  // [128]
    float* __restrict__ out,         // [B][128]
    int B, int ENV) {
    __shared__ float tile[CBLK * TSTR];   // 16.5 KB
    __shared__ int   list[CHUNK];         // 32 KB
    __shared__ int   cnt;

    const int t    = threadIdx.x;
    const int cg   = blockIdx.x >> 1;       // column group
    const int half = blockIdx.x & 1;        // which half of idx
    const int c0   = cg * CBLK;
    const int base = half * CHUNK;

    // Phase A: one float4 per thread. d = t>>3 (0..127), q = t&7 (8 x 4 cols).
    {
        int d = t >> 3;
        int q = t & 7;
        f32x4 v = *reinterpret_cast<const f32x4*>(
            &W[(size_t)d * ENV + c0 + q * 4]);
        float bv = bias[d];
        tile[(q * 4 + 0) * TSTR + d] = v.x + bv;
        tile[(q * 4 + 1) * TSTR + d] = v.y + bv;
        tile[(q * 4 + 2) * TSTR + d] = v.z + bv;
        tile[(q * 4 + 3) * TSTR + d] = v.w + bv;
    }
    if (t == 0) cnt = 0;
    __syncthreads();

    // Phase B: scan this block's half of idx (CHUNK ints = CHUNK/4 int4s)
    {
        const i32x4* idx4 = reinterpret_cast<const i32x4*>(idx);
        int nq = min(CHUNK, B - base) >> 2;
        #pragma unroll 2
        for (int q = t; q < nq; q += 1024) {
            i32x4 v = idx4[((size_t)base >> 2) + q];
            int i0 = base + q * 4;
            #pragma unroll
            for (int j = 0; j < 4; ++j) {
                int cl = v[j] - c0;
                if ((unsigned)cl < (unsigned)CBLK) {
                    int p = atomicAdd(&cnt, 1);
                    list[p] = ((i0 + j) << 5) | cl;
                }
            }
        }
    }
    __syncthreads();

    // Phase C: one row per wave-iteration, float2 per lane (512B store/wave)
    {
        const int wave = t >> 6;
        const int lane = t & 63;
        int n = cnt;
        for (int r = wave; r < n; r += 16) {
            int e  = list[r];
            int cl = e & 31;
            int i  = e >> 5;
            float2 val;
            val.x = tile[cl * TSTR + 2 * lane];
            val.y = tile[cl * TSTR + 2 * lane + 1];
            *reinterpret_cast<float2*>(&out[(size_t)i * 128 + 2 * lane]) = val;
        }
    }
}

// Fallback for unexpected shapes: direct gather.
__global__ void __launch_bounds__(256) onehot_linear_direct_kernel(
    const int* __restrict__ idx, const float* __restrict__ W,
    const float* __restrict__ bias, float* __restrict__ out,
    int B, int ENV, int EMB) {
    int total = B * EMB;
    for (int t = blockIdx.x * blockDim.x + threadIdx.x; t < total;
         t += gridDim.x * blockDim.x) {
        int i = t / EMB;
        int d = t - i * EMB;
        int c = idx[i];
        out[t] = W[(size_t)d * ENV + c] + bias[d];
    }
}

extern "C" void kernel_launch(void* const* d_in, const int* in_sizes, int n_in,
                              void* d_out, int out_size, void* d_ws, size_t ws_size,
                              hipStream_t stream) {
    const int*   idx  = (const int*)d_in[0];
    const float* W    = (const float*)d_in[1];
    const float* bias = (const float*)d_in[2];
    float*       out  = (float*)d_out;

    const int B   = in_sizes[0];
    const int EMB = in_sizes[2];
    const int ENV = in_sizes[1] / EMB;

    const bool fast = (EMB == 128) && (ENV % CBLK == 0) &&
                      (B == 2 * CHUNK);   // exact-shape specialization

    if (fast) {
        const int grid = (ENV / CBLK) * 2;   // 512 blocks: (column-group, half)
        onehot_fused_v3<<<grid, 1024, 0, stream>>>(idx, W, bias, out, B, ENV);
    } else {
        const int total = B * EMB;
        const int block = 256;
        const int grid  = min((total + block - 1) / block, 2048);
        onehot_linear_direct_kernel<<<grid, block, 0, stream>>>(
            idx, W, bias, out, B, ENV, EMB);
    }
}

// Round 8
// 10.514 us; speedup vs baseline: 1.0030x; 1.0030x over previous
//
#include <hip/hip_runtime.h>
#include <hip/hip_bf16.h>

// out[i, d] = W[d, idx[i]] + b[d]   (one-hot(idx) @ W^T + b)
// Single-dispatch owner-computes, v4: 512 blocks; block b owns
// (column-group cg = b>>2 of 64 cols, idx-quarter qt = b&3).
//   A) stage W[:, c0:c0+64] + bias into LDS transposed (2 float4/thread)
//   B) scan its quarter of idx: exactly ONE int4 per thread -> LDS match-list
//      (list[4096] == quarter size: can never overflow, any input)
//   C) waves drain list: out[i][:] = tile[idx[i]-c0][:] (float2/lane, 512B/wave)
// 1024 thr/block, 2 blocks/CU -> 32 waves/CU; exactly 2 barriers.
// vs R7: scan traffic halved (16MB -> 8MB total), scan depth 2 int4 -> 1 int4.

typedef float f32x4 __attribute__((ext_vector_type(4)));
typedef int   i32x4 __attribute__((ext_vector_type(4)));

#define CBLK   64     // env columns per block
#define TSTR   129    // tile stride: 129 % 32 == 1 -> <=2-way banks on writes
#define SPLITS 4      // idx quarters
#define CHUNK  4096   // idx ints per block (= B/SPLITS); list sized to match

__global__ void __launch_bounds__(1024) onehot_fused_v4(
    const int* __restrict__ idx,
    const float* __restrict__ W,     // [128][ENV]
    const float* __restrict__ bias,  // [128]
    float* __restrict__ out,         // [B][128]
    int B, int ENV) {
    __shared__ float tile[CBLK * TSTR];   // 33 KB
    __shared__ int   list[CHUNK];         // 16 KB
    __shared__ int   cnt;

    const int t    = threadIdx.x;
    const int cg   = blockIdx.x >> 2;       // column group (64 cols)
    const int qt   = blockIdx.x & 3;        // which quarter of idx
    const int c0   = cg * CBLK;
    const int base = qt * CHUNK;

    // Phase A: 128 rows x 64 cols = 2048 float4s; 2 per thread.
    #pragma unroll
    for (int k = 0; k < 2; ++k) {
        int f = t + k * 1024;
        int d = f >> 4;                 // 0..127
        int q = f & 15;                 // 16 float4-cols
        f32x4 v = *reinterpret_cast<const f32x4*>(
            &W[(size_t)d * ENV + c0 + q * 4]);
        float bv = bias[d];
        tile[(q * 4 + 0) * TSTR + d] = v.x + bv;
        tile[(q * 4 + 1) * TSTR + d] = v.y + bv;
        tile[(q * 4 + 2) * TSTR + d] = v.z + bv;
        tile[(q * 4 + 3) * TSTR + d] = v.w + bv;
    }
    if (t == 0) cnt = 0;
    __syncthreads();

    // Phase B: exactly one int4 per thread (CHUNK = 4 * 1024)
    {
        const i32x4* idx4 = reinterpret_cast<const i32x4*>(idx);
        i32x4 v = idx4[((size_t)base >> 2) + t];
        int i0 = base + t * 4;
        #pragma unroll
        for (int j = 0; j < 4; ++j) {
            int cl = v[j] - c0;
            if ((unsigned)cl < (unsigned)CBLK) {
                int p = atomicAdd(&cnt, 1);
                list[p] = ((i0 + j) << 6) | cl;
            }
        }
    }
    __syncthreads();

    // Phase C: one row per wave-iteration, float2 per lane (512B store/wave)
    {
        const int wave = t >> 6;
        const int lane = t & 63;
        int n = cnt;
        for (int r = wave; r < n; r += 16) {
            int e  = list[r];
            int cl = e & 63;
            int i  = e >> 6;
            float2 val;
            val.x = tile[cl * TSTR + 2 * lane];
            val.y = tile[cl * TSTR + 2 * lane + 1];
            *reinterpret_cast<float2*>(&out[(size_t)i * 128 + 2 * lane]) = val;
        }
    }
}

// Fallback for unexpected shapes: direct gather.
__global__ void __launch_bounds__(256) onehot_linear_direct_kernel(
    const int* __restrict__ idx, const float* __restrict__ W,
    const float* __restrict__ bias, float* __restrict__ out,
    int B, int ENV, int EMB) {
    int total = B * EMB;
    for (int t = blockIdx.x * blockDim.x + threadIdx.x; t < total;
         t += gridDim.x * blockDim.x) {
        int i = t / EMB;
        int d = t - i * EMB;
        int c = idx[i];
        out[t] = W[(size_t)d * ENV + c] + bias[d];
    }
}

extern "C" void kernel_launch(void* const* d_in, const int* in_sizes, int n_in,
                              void* d_out, int out_size, void* d_ws, size_t ws_size,
                              hipStream_t stream) {
    const int*   idx  = (const int*)d_in[0];
    const float* W    = (const float*)d_in[1];
    const float* bias = (const float*)d_in[2];
    float*       out  = (float*)d_out;

    const int B   = in_sizes[0];
    const int EMB = in_sizes[2];
    const int ENV = in_sizes[1] / EMB;

    const bool fast = (EMB == 128) && (ENV % CBLK == 0) &&
                      (B == SPLITS * CHUNK);   // exact-shape specialization

    if (fast) {
        const int grid = (ENV / CBLK) * SPLITS;   // 128 groups x 4 quarters = 512
        onehot_fused_v4<<<grid, 1024, 0, stream>>>(idx, W, bias, out, B, ENV);
    } else {
        const int total = B * EMB;
        const int block = 256;
        const int grid  = min((total + block - 1) / block, 2048);
        onehot_linear_direct_kernel<<<grid, block, 0, stream>>>(
            idx, W, bias, out, B, ENV, EMB);
    }
}